// Round 4
// baseline (597.941 us; speedup 1.0000x reference)
//
#include <hip/hip_runtime.h>
#include <hip/hip_bf16.h>

#define N_ROWS 16384
#define DIN_K  256
#define DOUT_K 64
#define M_COLS 16384
#define LOG2E  1.4426950408889634f

typedef __attribute__((ext_vector_type(8))) short short8;
typedef __attribute__((ext_vector_type(4))) float f32x4;

#define MFMA16 __builtin_amdgcn_mfma_f32_16x16x32_bf16
#define EXP2F  __builtin_amdgcn_exp2f
#define LOG2F  __builtin_amdgcn_logf

__device__ inline unsigned short f32_bf16_rne(float x) {
    unsigned u = __builtin_bit_cast(unsigned, x);
    u += 0x7fffu + ((u >> 16) & 1u);
    return (unsigned short)(u >> 16);
}
__device__ inline float bf16_f32(unsigned short h) {
    unsigned u = ((unsigned)h) << 16;
    return __builtin_bit_cast(float, u);
}

// ---------------------------------------------------------------------------
// Kernel 1: before = (X @ W) * log2(e); split to bf16 hi/lo; per-row exp bound
// ---------------------------------------------------------------------------
__global__ __launch_bounds__(256) void k_before(
    const float* __restrict__ X, const float* __restrict__ W,
    float* __restrict__ off2,
    unsigned short* __restrict__ bh, unsigned short* __restrict__ bl)
{
    const int row  = blockIdx.x * 4 + (threadIdx.x >> 6);
    const int lane = threadIdx.x & 63;
    const float* xr = X + (size_t)row * DIN_K;
    float acc = 0.f;
    #pragma unroll 8
    for (int d = 0; d < DIN_K; ++d)
        acc = fmaf(xr[d], W[d * DOUT_K + lane], acc);
    const float bs = acc * LOG2E;
    const unsigned short hs = f32_bf16_rne(bs);
    const float hf = bf16_f32(hs);
    const unsigned short ls = f32_bf16_rne(bs - hf);
    bh[row * DOUT_K + lane] = hs;
    bl[row * DOUT_K + lane] = ls;
    float t = fmaxf(bs, 0.f);
    #pragma unroll
    for (int m = 1; m < 64; m <<= 1) t += __shfl_xor(t, m, 64);
    if (lane == 0) off2[row] = t;
}

// ---------------------------------------------------------------------------
// Kernel 2: pack adjacency into MFMA A-fragment order, bf16 hi/lo (unchanged).
// chunk c, ks: lane l holds adj[k = ks*32 + (l>>4)*8 + i][c*16 + (l&15)]
// ---------------------------------------------------------------------------
__global__ __launch_bounds__(256) void k_pack(
    const float* __restrict__ A,
    unsigned short* __restrict__ ahp, unsigned short* __restrict__ alp)
{
    const int wid   = blockIdx.x * 4 + (threadIdx.x >> 6);  // 0..2047
    const int lane  = threadIdx.x & 63;
    const int chunk = wid >> 1, ks = wid & 1;
    const int col   = chunk * 16 + (lane & 15);
    const int kb    = ks * 32 + ((lane >> 4) * 8);
    const size_t base = ((size_t)(chunk * 2 + ks) * 64 + lane) * 8;
    #pragma unroll
    for (int i = 0; i < 8; ++i) {
        const float a = A[(size_t)(kb + i) * M_COLS + col];
        const unsigned short hs = f32_bf16_rne(a);
        ahp[base + i] = hs;
        alp[base + i] = f32_bf16_rne(a - bf16_f32(hs));
    }
}

// ---------------------------------------------------------------------------
// Shared tiling for k_denom / k_final:
//   grid 512 = 64 row-groups x 8 col-groups (cb = blockIdx.x & 7 -> XCD id,
//   so all blocks sharing a fragment slice land on one XCD's L2).
//   Block: 256 rows x 2048 cols, 8 waves x 32 rows; all waves share each
//   chunk's 4KB fragment data, staged in LDS via global_load_lds (2 chunks
//   per iteration, double-buffered, 2-phase barrier loop).
// ---------------------------------------------------------------------------
#define STAGE(b, c) {                                                        \
    const unsigned short* _g = (wave < 4 ? ahp : alp)                        \
        + (size_t)(c) * 1024 + (size_t)(threadIdx.x & 255) * 8;              \
    unsigned short* _l = (wave < 4) ? &abuf[b][wave * 512]                   \
                                    : &lbuf[b][(wave - 4) * 512];            \
    __builtin_amdgcn_global_load_lds(                                        \
        (const __attribute__((address_space(1))) void*)_g,                   \
        (__attribute__((address_space(3))) void*)_l, 16, 0, 0); }

#define FRAG(b, sub, H0, H1, L0, L1) {                                       \
    const int _o = (sub) * 1024 + lane * 8;                                  \
    H0 = *reinterpret_cast<const short8*>(&abuf[b][_o]);                     \
    H1 = *reinterpret_cast<const short8*>(&abuf[b][_o + 512]);               \
    L0 = *reinterpret_cast<const short8*>(&lbuf[b][_o]);                     \
    L1 = *reinterpret_cast<const short8*>(&lbuf[b][_o + 512]); }

#define LOAD_STATIONARY()                                                    \
    short8 bHf[2][2], bLf[2][2];                                             \
    _Pragma("unroll")                                                        \
    for (int rt = 0; rt < 2; ++rt)                                           \
        _Pragma("unroll")                                                    \
        for (int ks = 0; ks < 2; ++ks) {                                     \
            const size_t o = (size_t)(r0 + rt * 16 + lrow) * DOUT_K          \
                           + ks * 32 + lgrp * 8;                             \
            bHf[rt][ks] = *reinterpret_cast<const short8*>(bh + o);          \
            bLf[rt][ks] = *reinterpret_cast<const short8*>(bl + o);          \
        }

__global__ __launch_bounds__(512, 2) void k_denom(
    const unsigned short* __restrict__ bh, const unsigned short* __restrict__ bl,
    const unsigned short* __restrict__ ahp, const unsigned short* __restrict__ alp,
    const float* __restrict__ off2, float* __restrict__ partial)
{
    __shared__ unsigned short abuf[2][2048];
    __shared__ unsigned short lbuf[2][2048];
    const int wave = threadIdx.x >> 6;
    const int lane = threadIdx.x & 63;
    const int lrow = lane & 15;
    const int lgrp = lane >> 4;
    const int cb   = blockIdx.x & 7;
    const int rb   = blockIdx.x >> 3;
    const int r0   = rb * 256 + wave * 32;
    const int c0   = cb * 128;

    LOAD_STATIONARY();
    float negoff[2] = { -off2[r0 + lrow], -off2[r0 + 16 + lrow] };
    float lsum[2] = { 0.f, 0.f };

#define BODY1(H0, H1, L0, L1)                                                \
    _Pragma("unroll")                                                        \
    for (int rt = 0; rt < 2; ++rt) {                                         \
        f32x4 acc = { negoff[rt], negoff[rt], negoff[rt], negoff[rt] };      \
        acc = MFMA16(H0, bHf[rt][0], acc, 0, 0, 0);                          \
        acc = MFMA16(H1, bHf[rt][1], acc, 0, 0, 0);                          \
        acc = MFMA16(L0, bHf[rt][0], acc, 0, 0, 0);                          \
        acc = MFMA16(L1, bHf[rt][1], acc, 0, 0, 0);                          \
        acc = MFMA16(H0, bLf[rt][0], acc, 0, 0, 0);                          \
        acc = MFMA16(H1, bLf[rt][1], acc, 0, 0, 0);                          \
        lsum[rt] += (EXP2F(acc[0]) + EXP2F(acc[1]))                          \
                  + (EXP2F(acc[2]) + EXP2F(acc[3]));                         \
    }

    short8 H0, H1, L0, L1;
    STAGE(0, c0);
    __syncthreads();
    for (int it = 0; it < 64; ++it) {
        const int b = it & 1;
        if (it < 63) STAGE(b ^ 1, c0 + (it + 1) * 2);
        FRAG(b, 0, H0, H1, L0, L1);
        BODY1(H0, H1, L0, L1);
        FRAG(b, 1, H0, H1, L0, L1);
        BODY1(H0, H1, L0, L1);
        __syncthreads();
    }
#undef BODY1

    #pragma unroll
    for (int rt = 0; rt < 2; ++rt) {
        float v = lsum[rt];
        v += __shfl_xor(v, 16, 64);
        v += __shfl_xor(v, 32, 64);
        lsum[rt] = v;
    }
    if (lgrp == 0) {
        partial[(size_t)cb * N_ROWS + r0 + lrow]      = lsum[0];
        partial[(size_t)cb * N_ROWS + r0 + 16 + lrow] = lsum[1];
    }
}

__global__ __launch_bounds__(512, 2) void k_final(
    const unsigned short* __restrict__ bh, const unsigned short* __restrict__ bl,
    const unsigned short* __restrict__ ahp, const unsigned short* __restrict__ alp,
    const float* __restrict__ off2, const float* __restrict__ partial,
    float* __restrict__ out)
{
    __shared__ unsigned short abuf[2][2048];
    __shared__ unsigned short lbuf[2][2048];
    const int wave = threadIdx.x >> 6;
    const int lane = threadIdx.x & 63;
    const int lrow = lane & 15;
    const int lgrp = lane >> 4;
    const int cb   = blockIdx.x & 7;
    const int rb   = blockIdx.x >> 3;
    const int r0   = rb * 256 + wave * 32;
    const int c0   = cb * 128;

    LOAD_STATIONARY();
    float base2[2];
    #pragma unroll
    for (int rt = 0; rt < 2; ++rt) {
        const int row = r0 + rt * 16 + lrow;
        float tot = 0.f;
        #pragma unroll
        for (int p = 0; p < 8; ++p) tot += partial[(size_t)p * N_ROWS + row];
        base2[rt] = -off2[row] - LOG2F(tot);
    }

#define BODY2(H0, H1, L0, L1, c)                                             \
    _Pragma("unroll")                                                        \
    for (int rt = 0; rt < 2; ++rt) {                                         \
        f32x4 acc = { base2[rt], base2[rt], base2[rt], base2[rt] };          \
        acc = MFMA16(H0, bHf[rt][0], acc, 0, 0, 0);                          \
        acc = MFMA16(H1, bHf[rt][1], acc, 0, 0, 0);                          \
        acc = MFMA16(L0, bHf[rt][0], acc, 0, 0, 0);                          \
        acc = MFMA16(L1, bHf[rt][1], acc, 0, 0, 0);                          \
        acc = MFMA16(H0, bLf[rt][0], acc, 0, 0, 0);                          \
        acc = MFMA16(H1, bLf[rt][1], acc, 0, 0, 0);                          \
        f32x4 o4 = { EXP2F(acc[0]), EXP2F(acc[1]),                           \
                     EXP2F(acc[2]), EXP2F(acc[3]) };                         \
        const size_t _o = (size_t)(r0 + rt * 16 + lrow) * M_COLS             \
                        + (size_t)(c) * 16 + lgrp * 4;                       \
        __builtin_nontemporal_store(o4, reinterpret_cast<f32x4*>(out + _o)); \
    }

    short8 H0, H1, L0, L1;
    STAGE(0, c0);
    __syncthreads();
    for (int it = 0; it < 64; ++it) {
        const int b = it & 1;
        const int c = c0 + it * 2;
        if (it < 63) STAGE(b ^ 1, c + 2);
        FRAG(b, 0, H0, H1, L0, L1);
        BODY2(H0, H1, L0, L1, c);
        FRAG(b, 1, H0, H1, L0, L1);
        BODY2(H0, H1, L0, L1, c + 1);
        __syncthreads();
    }
#undef BODY2
}

extern "C" void kernel_launch(void* const* d_in, const int* in_sizes, int n_in,
                              void* d_out, int out_size, void* d_ws, size_t ws_size,
                              hipStream_t stream) {
    const float* X = (const float*)d_in[0];   // [16384, 256]
    const float* A = (const float*)d_in[1];   // [64, 16384]
    const float* W = (const float*)d_in[2];   // [256, 64]
    float* out = (float*)d_out;               // [16384, 16384]

    char* wsb = (char*)d_ws;
    float*          off2    = (float*)wsb;                                  // 64 KB
    unsigned short* bh      = (unsigned short*)(wsb + (1u << 16));          // 2 MB
    unsigned short* bl      = (unsigned short*)(wsb + (1u << 16) + 1u * (1u << 21));
    unsigned short* ahp     = (unsigned short*)(wsb + (1u << 16) + 2u * (1u << 21));
    unsigned short* alp     = (unsigned short*)(wsb + (1u << 16) + 3u * (1u << 21));
    float*          partial = (float*)(wsb + (1u << 16) + 4u * (1u << 21)); // 512 KB

    hipLaunchKernelGGL(k_before, dim3(N_ROWS / 4), dim3(256), 0, stream, X, W, off2, bh, bl);
    hipLaunchKernelGGL(k_pack,   dim3(512),        dim3(256), 0, stream, A, ahp, alp);
    hipLaunchKernelGGL(k_denom,  dim3(512),        dim3(512), 0, stream, bh, bl, ahp, alp, off2, partial);
    hipLaunchKernelGGL(k_final,  dim3(512),        dim3(512), 0, stream, bh, bl, ahp, alp, off2, partial, out);
}